// Round 3
// baseline (202.050 us; speedup 1.0000x reference)
//
#include <hip/hip_runtime.h>
#include <hip/hip_bf16.h>

#define NN 10000
#define EE 640000
#define CIN 128
#define COUT 128
#define HH 256
#define SLOT 160
#define BN_EPS 1e-5f
#define XPITCH 136   // shorts per staged x row (+8 pad) in stage1
#define HPITCH 264   // shorts per hbuf row (528 B pitch: conflict-free, measured 0)
#define S1BLOCKS 313 // (NN+31)/32

typedef __attribute__((ext_vector_type(8))) short short8x;
typedef __attribute__((ext_vector_type(4))) float floatx4;
typedef __attribute__((ext_vector_type(16))) float floatx16;

// ---- scratch layout in d_ws (bytes), 256B-aligned sections ----
constexpr size_t SZ_A    = (size_t)NN * HH * 4;          // fp32 A = xn@(W1t-W1b)+b1
constexpr size_t SZ_BB   = (size_t)NN * HH * 2;          // bf16 B = xn@W1b
constexpr size_t SZ_CNT  = (size_t)NN * 4;
constexpr size_t SZ_SLOT = ((size_t)NN * SLOT + 64) * 4;
constexpr size_t SZ_W2F  = (size_t)4 * 16 * 64 * 8 * 2;
constexpr size_t SZ_W1F  = (size_t)32 * 4 * 64 * 8 * 2;
constexpr size_t alup(size_t x) { return (x + 255) & ~(size_t)255; }
constexpr size_t OFF_A    = 0;
constexpr size_t OFF_BB   = alup(OFF_A + SZ_A);
constexpr size_t OFF_CNT  = alup(OFF_BB + SZ_BB);
constexpr size_t OFF_SLOT = alup(OFF_CNT + SZ_CNT);
constexpr size_t OFF_W2F  = alup(OFF_SLOT + SZ_SLOT);
constexpr size_t OFF_W1F  = alup(OFF_W2F + SZ_W2F);
constexpr size_t WS_NEED  = alup(OFF_W1F + SZ_W1F);

// Fallback scratch if ws_size < WS_NEED (kept out of the hot path).
__device__ __align__(256) char g_fb[WS_NEED];

__device__ __forceinline__ unsigned short f2bf(float f) {
    unsigned u = __float_as_uint(f);
    u += 0x7fffu + ((u >> 16) & 1u);   // RNE
    return (unsigned short)(u >> 16);
}
__device__ __forceinline__ float bf2f(unsigned short h) {
    return __uint_as_float(((unsigned)h) << 16);
}
// Packed f32x2 -> bf16x2 (v_cvt_pk_bf16_f32 on gfx950).
__device__ __forceinline__ unsigned pkbf(float a, float b) {
    __hip_bfloat162 t = __float22bfloat162_rn(make_float2(a, b));
    union { __hip_bfloat162 h; unsigned u; } cv; cv.h = t;
    return cv.u;
}

// Merged prep: zero cnt, swizzle W2 (32x32x16 B-frag order), fold+swizzle W1.
__global__ void prep_kernel(const float* __restrict__ W1, const float* __restrict__ W2,
                            int* __restrict__ gcnt, unsigned short* __restrict__ gW2f,
                            unsigned short* __restrict__ gW1f) {
    const int b = blockIdx.x, tid = threadIdx.x;
    if (b < 40) {
        int i = b * 256 + tid;
        if (i < NN) gcnt[i] = 0;
        return;
    }
    if (b < 56) {
        int idx = (b - 40) * 256 + tid;        // 0..4095
        int lane = idx & 63;
        int l31 = lane & 31, half = lane >> 5;
        int rest = idx >> 6;                   // 0..63
        int k0 = rest & 15, cg = rest >> 4;
        unsigned short frag[8];
        #pragma unroll
        for (int j = 0; j < 8; j++)
            frag[j] = f2bf(W2[(k0 * 16 + half * 8 + j) * COUT + cg * 32 + l31]);
        *(short8x*)(gW2f + (size_t)idx * 8) = *(short8x*)frag;
        return;
    }
    int idx = (b - 56) * 256 + tid;            // 0..8191
    int lane = idx & 63;
    int quad = lane >> 4, m = lane & 15;
    int t = idx >> 8, k0 = (idx >> 6) & 3;
    int c = t * 16 + m;                        // global col 0..511
    unsigned short frag[8];
    #pragma unroll
    for (int j = 0; j < 8; j++) {
        int k = k0 * 32 + quad * 8 + j;
        float v = (c < 256) ? (W1[k * HH + c] - W1[(k + CIN) * HH + c])
                            : W1[(k + CIN) * HH + (c - 256)];
        frag[j] = f2bf(v);
    }
    *(short8x*)(gW1f + (size_t)idx * 8) = *(short8x*)frag;
}

// Fused: blocks [0,S1BLOCKS) run stage1 (MFMA: [A|B] = xn @ W1f, 32 nodes/block);
// blocks [S1BLOCKS, S1BLOCKS+625) run the edge-slot scatter. Independent outputs.
__global__ __launch_bounds__(256) void stage1_scatter_kernel(
    const float* __restrict__ x, const float* __restrict__ gamma,
    const float* __restrict__ beta, const float* __restrict__ mean,
    const float* __restrict__ var, const float* __restrict__ b1,
    const int* __restrict__ ei,
    float* __restrict__ gA, unsigned short* __restrict__ gBb,
    int* __restrict__ gcnt, int* __restrict__ gslots,
    const unsigned short* __restrict__ gW1f)
{
    if (blockIdx.x >= S1BLOCKS) {              // ---- scatter part ----
        int t = (blockIdx.x - S1BLOCKS) * 256 + threadIdx.x;
        int e = t * 4;
        if (e < EE) {
            int4 s4 = *(const int4*)(ei + e);
            int4 d4 = *(const int4*)(ei + EE + e);
            int p;
            p = atomicAdd(&gcnt[d4.x], 1); if (p < SLOT) gslots[d4.x * SLOT + p] = s4.x;
            p = atomicAdd(&gcnt[d4.y], 1); if (p < SLOT) gslots[d4.y * SLOT + p] = s4.y;
            p = atomicAdd(&gcnt[d4.z], 1); if (p < SLOT) gslots[d4.z * SLOT + p] = s4.z;
            p = atomicAdd(&gcnt[d4.w], 1); if (p < SLOT) gslots[d4.w * SLOT + p] = s4.w;
        }
        return;
    }
    // ---- stage1 part ----
    __shared__ unsigned short xh[32 * XPITCH];
    __shared__ unsigned short xl[32 * XPITCH];
    __shared__ float s_lds[CIN], t_lds[CIN];
    const int tid = threadIdx.x;
    const int w = tid >> 6, lane = tid & 63;
    const int m = lane & 15, quad = lane >> 4;
    if (tid < CIN) {
        float s = gamma[tid] * rsqrtf(var[tid] + BN_EPS);
        s_lds[tid] = s;
        t_lds[tid] = beta[tid] - mean[tid] * s;
    }
    __syncthreads();
    const int mbase = blockIdx.x * 32;
    #pragma unroll
    for (int it = 0; it < 4; it++) {
        int slot = it * 256 + tid;
        int n = slot >> 5;
        int k = (slot & 31) * 4;
        int node = mbase + n;
        float4 v = make_float4(0.f, 0.f, 0.f, 0.f);
        if (node < NN) v = *(const float4*)(x + (size_t)node * CIN + k);
        float f[4] = {v.x, v.y, v.z, v.w};
        ushort4 uh, ul;
        unsigned short hb;
        float fn;
        fn = f[0] * s_lds[k + 0] + t_lds[k + 0]; hb = f2bf(fn); uh.x = hb; ul.x = f2bf(fn - bf2f(hb));
        fn = f[1] * s_lds[k + 1] + t_lds[k + 1]; hb = f2bf(fn); uh.y = hb; ul.y = f2bf(fn - bf2f(hb));
        fn = f[2] * s_lds[k + 2] + t_lds[k + 2]; hb = f2bf(fn); uh.z = hb; ul.z = f2bf(fn - bf2f(hb));
        fn = f[3] * s_lds[k + 3] + t_lds[k + 3]; hb = f2bf(fn); uh.w = hb; ul.w = f2bf(fn - bf2f(hb));
        *(ushort4*)(xh + n * XPITCH + k) = uh;
        *(ushort4*)(xl + n * XPITCH + k) = ul;
    }
    __syncthreads();

    floatx4 acc[2][8];
    #pragma unroll
    for (int mt = 0; mt < 2; mt++)
        #pragma unroll
        for (int nt = 0; nt < 8; nt++)
            acc[mt][nt] = (floatx4){0.f, 0.f, 0.f, 0.f};

    #pragma unroll
    for (int k0 = 0; k0 < 4; k0++) {
        short8x wf[8];
        #pragma unroll
        for (int nt = 0; nt < 8; nt++) {
            int t = w * 8 + nt;
            wf[nt] = *(const short8x*)(gW1f + (size_t)((t * 4 + k0) * 64 + lane) * 8);
        }
        #pragma unroll
        for (int mt = 0; mt < 2; mt++) {
            const unsigned short* rp = xh + (mt * 16 + m) * XPITCH + k0 * 32 + quad * 8;
            const unsigned short* lp = xl + (mt * 16 + m) * XPITCH + k0 * 32 + quad * 8;
            short8x ah = *(const short8x*)rp;
            short8x al = *(const short8x*)lp;
            #pragma unroll
            for (int nt = 0; nt < 8; nt++) {
                acc[mt][nt] = __builtin_amdgcn_mfma_f32_16x16x32_bf16(al, wf[nt], acc[mt][nt], 0, 0, 0);
                acc[mt][nt] = __builtin_amdgcn_mfma_f32_16x16x32_bf16(ah, wf[nt], acc[mt][nt], 0, 0, 0);
            }
        }
    }
    const int colbase = w * 128;
    #pragma unroll
    for (int mt = 0; mt < 2; mt++) {
        #pragma unroll
        for (int nt = 0; nt < 8; nt++) {
            int col = colbase + nt * 16 + m;
            #pragma unroll
            for (int j = 0; j < 4; j++) {
                int node = mbase + mt * 16 + quad * 4 + j;
                if (node < NN) {
                    float v = acc[mt][nt][j];
                    if (col < 256) gA[(size_t)node * HH + col] = v + b1[col];
                    else           gBb[(size_t)node * HH + (col - 256)] = f2bf(v);
                }
            }
        }
    }
}

// Main kernel v4: 256 threads = 4 waves; 32-edge periods; 32x32x16 MFMA.
// Double-buffered hbuf (two DISTINCT static arrays so alias analysis lets the
// scheduler interleave produce ds_writes with consume ds_reads/MFMA) and ONE
// barrier per period: region p = { produce(tile p+1 -> other buf) [VALU],
// MFMA(tile p <- current buf) [MFMA pipe], gather(tile p+2) [VMEM] } -> barrier.
// A buffer written in region p+? is re-written two regions after its last read,
// with a barrier in between -> safe with a single barrier per region.
__global__ __launch_bounds__(256, 4) void edge_kernel(
    const float* __restrict__ b2, float* __restrict__ out,
    const float* __restrict__ gA, const unsigned short* __restrict__ gBb,
    const int* __restrict__ gcnt, const int* __restrict__ gslots,
    const unsigned short* __restrict__ gW2f)
{
    __shared__ unsigned short hbA[32 * HPITCH];    // 16.9 KB
    __shared__ unsigned short hbB[32 * HPITCH];    // 16.9 KB
    __shared__ int sbuf[SLOT];
    const int tid = threadIdx.x;
    const int w = tid >> 6, lane = tid & 63;
    const int l31 = lane & 31, half = lane >> 5;
    const unsigned laneoff = (unsigned)lane << 3;  // lane*8 bytes

    // Full-K W2 B-frags for col-group w: 16 x short8x = 64 regs (AGPR-eligible).
    short8x bfrag[16];
    #pragma unroll
    for (int k0 = 0; k0 < 16; k0++)
        bfrag[k0] = *(const short8x*)(gW2f + (size_t)((w * 16 + k0) * 64 + lane) * 8);
    const float b2v = b2[w * 32 + l31];

#define GATHER(P) do {                                                             \
        int tbb = (P) << 5;                                                        \
        _Pragma("unroll")                                                          \
        for (int q = 0; q < 8; q++) {                                              \
            int er = tbb + w * 8 + q;                                              \
            int sv = (er < deg) ? sbuf[er] : 0;                                    \
            bv[q] = *(const uint2*)((const char*)gBb + (((unsigned)sv << 9) | laneoff)); \
        }                                                                          \
    } while (0)

#define PRODUCE(HB) do {                                                           \
        _Pragma("unroll")                                                          \
        for (int q = 0; q < 8; q++) {                                              \
            uint2 b = bv[q];                                                       \
            float f0 = __uint_as_float(b.x << 16);                                 \
            float f1 = __uint_as_float(b.x & 0xffff0000u);                         \
            float f2 = __uint_as_float(b.y << 16);                                 \
            float f3 = __uint_as_float(b.y & 0xffff0000u);                         \
            uint2 hv;                                                              \
            hv.x = pkbf(fmaxf(av.x + f0, 0.f), fmaxf(av.y + f1, 0.f));             \
            hv.y = pkbf(fmaxf(av.z + f2, 0.f), fmaxf(av.w + f3, 0.f));             \
            *(uint2*)((HB) + (w * 8 + q) * HPITCH + (lane << 2)) = hv;             \
        }                                                                          \
    } while (0)

#define MFMA_RED(HB, TB) do {                                                      \
        const unsigned short* ha = (HB) + l31 * HPITCH + (half << 3);              \
        floatx16 acc;                                                              \
        _Pragma("unroll") for (int j = 0; j < 16; j++) acc[j] = 0.f;               \
        _Pragma("unroll")                                                          \
        for (int k0 = 0; k0 < 16; k0++) {                                          \
            short8x af = *(const short8x*)(ha + k0 * 16);                          \
            acc = __builtin_amdgcn_mfma_f32_32x32x16_bf16(af, bfrag[k0], acc, 0, 0, 0); \
        }                                                                          \
        if ((TB) + 32 <= deg) {                                                    \
            _Pragma("unroll") for (int j = 0; j < 16; j++) rm = fmaxf(rm, acc[j]); \
        } else {                                                                   \
            _Pragma("unroll")                                                      \
            for (int j = 0; j < 16; j++) {                                         \
                int rr = (TB) + (j & 3) + ((j >> 2) << 3) + (half << 2);           \
                if (rr < deg) rm = fmaxf(rm, acc[j]);                              \
            }                                                                      \
        }                                                                          \
    } while (0)

    for (int g = 0; g < 4; g++) {
        const int node = blockIdx.x * 4 + g;
        int deg = gcnt[node]; if (deg > SLOT) deg = SLOT;
        const float4 av = *(const float4*)(gA + (size_t)node * HH + lane * 4);
        if (tid < deg) sbuf[tid] = gslots[node * SLOT + tid];
        __syncthreads();                  // sbuf ready; prev node done with hbufs
        float rm = -INFINITY;
        if (deg > 0) {
            const int ntp = (deg + 31) >> 5;
            uint2 bv[8];
            GATHER(0);
            PRODUCE(hbA);                 // tile 0
            if (ntp > 1) GATHER(1);
            __syncthreads();              // tile 0 visible everywhere
            int p = 0;
            for (;;) {
                if (p + 1 < ntp) PRODUCE(hbB);      // tile p+1 (independent of MFMA below)
                MFMA_RED(hbA, p << 5);              // tile p
                if (p + 2 < ntp) GATHER(p + 2);
                __syncthreads();
                if (++p >= ntp) break;
                if (p + 1 < ntp) PRODUCE(hbA);
                MFMA_RED(hbB, p << 5);
                if (p + 2 < ntp) GATHER(p + 2);
                __syncthreads();
                if (++p >= ntp) break;
            }
        }
        // lanes l and l+32 hold the same col, disjoint rows -> one xor-32 combine.
        rm = fmaxf(rm, __shfl_xor(rm, 32));
        if (half == 0)
            out[(size_t)node * COUT + w * 32 + l31] = (deg > 0) ? fmaxf(rm + b2v, 0.f) : 0.f;
    }
#undef GATHER
#undef PRODUCE
#undef MFMA_RED
}

extern "C" void kernel_launch(void* const* d_in, const int* in_sizes, int n_in,
                              void* d_out, int out_size, void* d_ws, size_t ws_size,
                              hipStream_t stream) {
    const float* x      = (const float*)d_in[0];
    const int*   ei     = (const int*)d_in[1];
    const float* gamma  = (const float*)d_in[2];
    const float* beta   = (const float*)d_in[3];
    const float* mean   = (const float*)d_in[4];
    const float* var    = (const float*)d_in[5];
    const float* W1     = (const float*)d_in[6];
    const float* b1     = (const float*)d_in[7];
    const float* W2     = (const float*)d_in[8];
    const float* b2     = (const float*)d_in[9];
    float* out = (float*)d_out;

    // Scratch: use the harness workspace (not re-poisoned between iterations);
    // fall back to a __device__ block only if ws is too small.
    char* base;
    if (ws_size >= WS_NEED && d_ws != nullptr) {
        base = (char*)d_ws;
    } else {
        void* p = nullptr;
        hipGetSymbolAddress(&p, HIP_SYMBOL(g_fb));
        base = (char*)p;
    }
    float*          gA     = (float*)(base + OFF_A);
    unsigned short* gBb    = (unsigned short*)(base + OFF_BB);
    int*            gcnt   = (int*)(base + OFF_CNT);
    int*            gslots = (int*)(base + OFF_SLOT);
    unsigned short* gW2f   = (unsigned short*)(base + OFF_W2F);
    unsigned short* gW1f   = (unsigned short*)(base + OFF_W1F);

    prep_kernel<<<88, 256, 0, stream>>>(W1, W2, gcnt, gW2f, gW1f);
    stage1_scatter_kernel<<<S1BLOCKS + 625, 256, 0, stream>>>(
        x, gamma, beta, mean, var, b1, ei, gA, gBb, gcnt, gslots, gW1f);
    edge_kernel<<<NN / 4, 256, 0, stream>>>(b2, out, gA, gBb, gcnt, gslots, gW2f);
}